// Round 6
// baseline (180.056 us; speedup 1.0000x reference)
//
#include <hip/hip_runtime.h>
#include <cstdint>
#include <cstddef>

typedef __bf16 bf16;
typedef __bf16 bf16x4 __attribute__((ext_vector_type(4)));
typedef __bf16 bf16x8 __attribute__((ext_vector_type(8)));
typedef float floatx4 __attribute__((ext_vector_type(4)));
typedef int intx8 __attribute__((ext_vector_type(8)));

#define NB 4096   // batch
#define ND 2048   // feature dim
#define NCLS 64   // classes
#define TSTRIDE 144  // sim epilogue LDS row stride (bytes), 16B-aligned
#define OS 136       // recon epilogue LDS row stride (bf16 elems, 272 B)

// ---------------------------------------------------------------- staging ---
__device__ __forceinline__ void stage16(const void* g, void* l) {
  // async global -> LDS, 16B per lane, LDS dest = wave-uniform base + lane*16
  __builtin_amdgcn_global_load_lds(
      (__attribute__((address_space(1))) unsigned int*)g,
      (__attribute__((address_space(3))) unsigned int*)l, 16, 0, 0);
}

// fp8 e4m3 (OCP) converts, RNE via V_CVT_PK_FP8_F32
__device__ __forceinline__ unsigned char fp8x1(float f) {
  return (unsigned char)(__builtin_amdgcn_cvt_pk_fp8_f32(f, f, 0, false) & 0xFF);
}
__device__ __forceinline__ int fp8x4(float f0, float f1, float f2, float f3) {
  int d = __builtin_amdgcn_cvt_pk_fp8_f32(f0, f1, 0, false);
  return __builtin_amdgcn_cvt_pk_fp8_f32(f2, f3, d, true);
}

// stage one K=128 step of A(128 rows) and B(128 rows) into As/Bs (16 KB each).
// LDS rows of 128 B (8 x 16B chunks), chunk XOR-swizzled by (row&7).
__device__ __forceinline__ void stage_step(const unsigned char* __restrict__ A,
                                           const unsigned char* __restrict__ B,
                                           int K, int m0, int n0, int k0,
                                           unsigned char* As,
                                           unsigned char* Bs) {
  const int t = threadIdx.x;
  const int w = t >> 6, lane = t & 63;
#pragma unroll
  for (int q = 0; q < 4; ++q) {
    const int slot = w * 256 + q * 64 + lane;
    const int row = slot >> 3;
    const int cc = (slot & 7) ^ (row & 7);  // swizzled global chunk
    stage16(A + (size_t)(m0 + row) * K + (k0 + cc * 16),
            As + (w * 256 + q * 64) * 16);
  }
#pragma unroll
  for (int q = 0; q < 4; ++q) {
    const int slot = w * 256 + q * 64 + lane;
    const int row = slot >> 3;
    const int cc = (slot & 7) ^ (row & 7);
    stage16(B + (size_t)(n0 + row) * K + (k0 + cc * 16),
            Bs + (w * 256 + q * 64) * 16);
  }
}

// ------------------------------------------------------------- GEMM core ----
// C[128][128] = A[128][K] * B[128][K]^T, fp8 inputs, fp32 accum via
// mfma_scale 16x16x128 (scales = 1.0 -> byte 127).
// Double-buffered K-loop, ONE barrier per iteration. Inner step interleaves
// ds_read and MFMA (reads of later frags behind MFMAs of earlier frags) to
// break the post-barrier convoy where LDS and MFMA phases serialize.
#define READ_A(i)                                                       \
  {                                                                     \
    const int row = wm * 64 + (i)*16 + lm;                              \
    const int c0 = (quad * 2) ^ (row & 7);                              \
    const int4 lo = *(const int4*)(Ac + row * 128 + c0 * 16);           \
    const int4 hi = *(const int4*)(Ac + row * 128 + (c0 ^ 1) * 16);     \
    af[i][0] = lo.x; af[i][1] = lo.y; af[i][2] = lo.z; af[i][3] = lo.w; \
    af[i][4] = hi.x; af[i][5] = hi.y; af[i][6] = hi.z; af[i][7] = hi.w; \
  }
#define READ_B(i)                                                            \
  {                                                                          \
    const int row = wn * 64 + (i)*16 + lm;                                   \
    const int c0 = (quad * 2) ^ (row & 7);                                   \
    const int4 lo = *(const int4*)(Bc + row * 128 + c0 * 16);                \
    const int4 hi = *(const int4*)(Bc + row * 128 + (c0 ^ 1) * 16);          \
    bfr[i][0] = lo.x; bfr[i][1] = lo.y; bfr[i][2] = lo.z; bfr[i][3] = lo.w;  \
    bfr[i][4] = hi.x; bfr[i][5] = hi.y; bfr[i][6] = hi.z; bfr[i][7] = hi.w;  \
  }
#define MFMA(mi, ni)                                                \
  acc[mi][ni] = __builtin_amdgcn_mfma_scale_f32_16x16x128_f8f6f4(   \
      af[mi], bfr[ni], acc[mi][ni], 0, 0, 0, 127, 0, 127)

__device__ __forceinline__ void gemm_core8(const unsigned char* __restrict__ A,
                                           const unsigned char* __restrict__ B,
                                           int K, int m0, int n0,
                                           unsigned char* As0, unsigned char* Bs0,
                                           unsigned char* As1, unsigned char* Bs1,
                                           floatx4 acc[4][4]) {
  const int t = threadIdx.x;
  const int w = t >> 6;
  const int lane = t & 63;
  const int wm = w >> 1, wn = w & 1;
  const int lm = lane & 15, quad = lane >> 4;
  const int nk = K >> 7;

  stage_step(A, B, K, m0, n0, 0, As0, Bs0);

  for (int k = 0; k < nk; ++k) {
    __syncthreads();  // drains vmcnt(0): buf[k&1] staged; prior reads done
    if (k + 1 < nk)
      stage_step(A, B, K, m0, n0, (k + 1) << 7, (k & 1) ? As0 : As1,
                 (k & 1) ? Bs0 : Bs1);
    unsigned char* Ac = (k & 1) ? As1 : As0;
    unsigned char* Bc = (k & 1) ? Bs1 : Bs0;

    intx8 af[4], bfr[4];
    READ_A(0); READ_A(1); READ_B(0); READ_B(1);
    MFMA(0, 0); MFMA(0, 1); MFMA(1, 0); MFMA(1, 1);
    READ_A(2); READ_A(3);
    MFMA(2, 0); MFMA(2, 1); MFMA(3, 0); MFMA(3, 1);
    READ_B(2); READ_B(3);
    MFMA(0, 2); MFMA(0, 3); MFMA(1, 2); MFMA(1, 3);
    MFMA(2, 2); MFMA(2, 3); MFMA(3, 2); MFMA(3, 3);
  }
}

// ---------------------------------------------------------------- kernels ---

// Fused prep: blocks [0,NB): LayerNorm (x -> XN8 = fp8(x_norm*32), XB16 =
// bf16(x), lrow=0, contrib, maskcol); blocks [NB, NB+2048): transpose
// x -> XBT8; blocks [NB+2048, NB+3072): y_mix one-hot output.
__global__ __launch_bounds__(256) void prep_kernel(
    const float* __restrict__ x, const int* __restrict__ y,
    const float* __restrict__ alpha, const int* __restrict__ beta_idx,
    const float* __restrict__ c, const int* __restrict__ fs,
    unsigned char* __restrict__ XN8, unsigned char* __restrict__ XBT8,
    bf16* __restrict__ XB16, float* __restrict__ lrow,
    float* __restrict__ contrib, int* __restrict__ maskcol,
    float* __restrict__ out) {
  __shared__ float tile[64][65];
  const int t = threadIdx.x;

  if (blockIdx.x < NB) {
    // ---------------- LayerNorm branch
    const int row = blockIdx.x;
    const float4* xr = (const float4*)(x + (size_t)row * ND);
    float4 v0 = xr[t], v1 = xr[t + 256];
    float s = v0.x + v0.y + v0.z + v0.w + v1.x + v1.y + v1.z + v1.w;
    float q = v0.x * v0.x + v0.y * v0.y + v0.z * v0.z + v0.w * v0.w +
              v1.x * v1.x + v1.y * v1.y + v1.z * v1.z + v1.w * v1.w;
#pragma unroll
    for (int o = 32; o > 0; o >>= 1) {
      s += __shfl_down(s, o);
      q += __shfl_down(q, o);
    }
    const int w = t >> 6;
    if ((t & 63) == 0) { tile[0][w] = s; tile[1][w] = q; }
    __syncthreads();
    s = tile[0][0] + tile[0][1] + tile[0][2] + tile[0][3];
    q = tile[1][0] + tile[1][1] + tile[1][2] + tile[1][3];
    const float mu = s * (1.0f / ND);
    const float var = q * (1.0f / ND) - mu * mu;
    const float sc =
        rsqrtf(var + 1e-5f) * 0.02209708691207961f * 32.0f;  // /sqrt(2048)*32

    int* orow = (int*)(XN8 + (size_t)row * ND);
    orow[t] = fp8x4((v0.x - mu) * sc, (v0.y - mu) * sc, (v0.z - mu) * sc,
                    (v0.w - mu) * sc);
    orow[256 + t] = fp8x4((v1.x - mu) * sc, (v1.y - mu) * sc, (v1.z - mu) * sc,
                          (v1.w - mu) * sc);

    bf16x4 b0, b1;
    b0[0] = (bf16)v0.x; b0[1] = (bf16)v0.y; b0[2] = (bf16)v0.z; b0[3] = (bf16)v0.w;
    b1[0] = (bf16)v1.x; b1[1] = (bf16)v1.y; b1[2] = (bf16)v1.z; b1[3] = (bf16)v1.w;
    *(bf16x4*)(XB16 + (size_t)row * ND + t * 4) = b0;
    *(bf16x4*)(XB16 + (size_t)row * ND + 1024 + t * 4) = b1;

    if (t == 0) {
      lrow[row] = 0.0f;
      const int yi = y[row];
      contrib[row] = c[yi];
      maskcol[row] = fs[yi];
    }
  } else if (blockIdx.x < NB + 2048) {
    // ---------------- transpose branch: x (NB x ND fp32) -> XBT8 (ND x NB)
    const int b2 = blockIdx.x - NB;
    const int rb = b2 & 63;  // batch tile (0..63)
    const int cb = b2 >> 6;  // feature tile (0..31)
    const int tx = t & 63, ty = t >> 6;
#pragma unroll
    for (int rr = ty; rr < 64; rr += 4)
      tile[rr][tx] = x[(size_t)(rb * 64 + rr) * ND + cb * 64 + tx];
    __syncthreads();
    const int ro = t >> 2;  // out row within feature tile
    const int co = t & 3;   // 16-byte chunk within batch tile
    int4 v;
    {
      const int j = co * 16;
      v.x = fp8x4(tile[j + 0][ro], tile[j + 1][ro], tile[j + 2][ro], tile[j + 3][ro]);
      v.y = fp8x4(tile[j + 4][ro], tile[j + 5][ro], tile[j + 6][ro], tile[j + 7][ro]);
      v.z = fp8x4(tile[j + 8][ro], tile[j + 9][ro], tile[j + 10][ro], tile[j + 11][ro]);
      v.w = fp8x4(tile[j + 12][ro], tile[j + 13][ro], tile[j + 14][ro], tile[j + 15][ro]);
    }
    *(int4*)(XBT8 + (size_t)(cb * 64 + ro) * NB + rb * 64 + co * 16) = v;
  } else {
    // ---------------- y_mix branch: out[NB*ND + i*NCLS + cls]
    const int b3 = blockIdx.x - (NB + 2048);
    const int row = b3 * 4 + (t >> 6);
    const int cls = t & 63;
    const float a = alpha[row];
    const int bi = beta_idx[row];
    const int yi = y[row], yb = y[bi];
    out[(size_t)NB * ND + (size_t)row * NCLS + cls] =
        a * (cls == yi ? 1.0f : 0.0f) + (1.0f - a) * (cls == yb ? 1.0f : 0.0f);
  }
}

// GEMM1 (triangular): for block (bi<=bj), acc = 1024*sim; e = exp(acc/1024);
// write Pn tile (bi,bj) fp8 w/ col mask of Bj and Pt tile (bj,bi) w/ col mask
// of Bi; accumulate row sums of unquantized e.
__global__ __launch_bounds__(256) void gemm_sim_kernel(
    const unsigned char* __restrict__ XN8, unsigned char* __restrict__ P8,
    float* __restrict__ lrow, const int* __restrict__ maskcol) {
  __shared__ unsigned char smem[65536];
  unsigned char* As0 = smem;
  unsigned char* Bs0 = smem + 16384;
  unsigned char* As1 = smem + 32768;
  unsigned char* Bs1 = smem + 49152;

  // triangular decode: b = bj*(bj+1)/2 + bi, bi <= bj
  const int b = blockIdx.x;
  int bj = (int)((sqrtf(8.0f * (float)b + 1.0f) - 1.0f) * 0.5f);
  while ((bj + 1) * (bj + 2) / 2 <= b) ++bj;
  while (bj * (bj + 1) / 2 > b) --bj;
  const int bi = b - bj * (bj + 1) / 2;
  const int m0 = bi * 128, n0 = bj * 128;

  floatx4 acc[4][4];
#pragma unroll
  for (int i = 0; i < 4; ++i)
#pragma unroll
    for (int j = 0; j < 4; ++j) acc[i][j] = 0.0f;

  gemm_core8(XN8, XN8, ND, m0, n0, As0, Bs0, As1, Bs1, acc);

  const int t = threadIdx.x, w = t >> 6, lane = t & 63;
  const int wm = w >> 1, wn = w & 1, lm = lane & 15, quad = lane >> 4;

  int cmj[4];
#pragma unroll
  for (int ni = 0; ni < 4; ++ni) cmj[ni] = maskcol[n0 + wn * 64 + ni * 16 + lm];
  int rmk[4][4];
#pragma unroll
  for (int mi = 0; mi < 4; ++mi)
#pragma unroll
    for (int r = 0; r < 4; ++r)
      rmk[mi][r] = maskcol[m0 + wm * 64 + mi * 16 + quad * 4 + r];

  // exp in place (diag -> 0), Pn row sums
  float rs[4][4];
#pragma unroll
  for (int mi = 0; mi < 4; ++mi)
#pragma unroll
    for (int r = 0; r < 4; ++r) rs[mi][r] = 0.0f;

#pragma unroll
  for (int ni = 0; ni < 4; ++ni) {
    const int gcol = n0 + wn * 64 + ni * 16 + lm;
#pragma unroll
    for (int mi = 0; mi < 4; ++mi) {
#pragma unroll
      for (int r = 0; r < 4; ++r) {
        const int grow = m0 + wm * 64 + mi * 16 + quad * 4 + r;
        float e = (grow == gcol) ? 0.0f
                                 : __expf(acc[mi][ni][r] * 0.0009765625f);
        acc[mi][ni][r] = e;
        rs[mi][r] += cmj[ni] ? 0.0f : e;
      }
    }
  }
#pragma unroll
  for (int mi = 0; mi < 4; ++mi)
#pragma unroll
    for (int r = 0; r < 4; ++r) {
      float vsum = rs[mi][r];
      vsum += __shfl_xor(vsum, 1);
      vsum += __shfl_xor(vsum, 2);
      vsum += __shfl_xor(vsum, 4);
      vsum += __shfl_xor(vsum, 8);
      if (lm == 0)
        atomicAdd(&lrow[m0 + wm * 64 + mi * 16 + quad * 4 + r], vsum);
    }

  // ---- Pn tile -> LDS (byte scatter) -> coalesced b128 store at (bi,bj)
  __syncthreads();  // core's K-loop ended without a barrier; LDS now reusable
#pragma unroll
  for (int ni = 0; ni < 4; ++ni) {
    const int col = wn * 64 + ni * 16 + lm;
#pragma unroll
    for (int mi = 0; mi < 4; ++mi)
#pragma unroll
      for (int r = 0; r < 4; ++r) {
        const int row = wm * 64 + mi * 16 + quad * 4 + r;
        smem[row * TSTRIDE + col] = fp8x1(cmj[ni] ? 0.0f : acc[mi][ni][r]);
      }
  }
  __syncthreads();
#pragma unroll
  for (int it = 0; it < 4; ++it) {
    const int row = it * 32 + (t >> 3), ch = t & 7;
    int4 v = *(const int4*)(smem + row * TSTRIDE + ch * 16);
    *(int4*)(P8 + (size_t)(m0 + row) * NB + n0 + ch * 16) = v;
  }

  if (bi != bj) {
    __syncthreads();
    // ---- Pt tile: in-lane dword pack (4 rows = 4 consecutive Pt cols)
#pragma unroll
    for (int ni = 0; ni < 4; ++ni) {
      const int tc = wn * 64 + ni * 16 + lm;  // Pt row = original col
      float cs = 0.0f;
#pragma unroll
      for (int mi = 0; mi < 4; ++mi) {
        float g0 = rmk[mi][0] ? 0.0f : acc[mi][ni][0];
        float g1 = rmk[mi][1] ? 0.0f : acc[mi][ni][1];
        float g2 = rmk[mi][2] ? 0.0f : acc[mi][ni][2];
        float g3 = rmk[mi][3] ? 0.0f : acc[mi][ni][3];
        cs += g0 + g1 + g2 + g3;
        *(int*)(smem + tc * TSTRIDE + wm * 64 + mi * 16 + quad * 4) =
            fp8x4(g0, g1, g2, g3);
      }
      cs += __shfl_xor(cs, 16);
      cs += __shfl_xor(cs, 32);
      if (quad == 0) atomicAdd(&lrow[n0 + tc], cs);
    }
    __syncthreads();
#pragma unroll
    for (int it = 0; it < 4; ++it) {
      const int row = it * 32 + (t >> 3), ch = t & 7;
      int4 v = *(const int4*)(smem + row * TSTRIDE + ch * 16);
      *(int4*)(P8 + (size_t)(n0 + row) * NB + m0 + ch * 16) = v;
    }
  }
}

// GEMM2: R(bf16) = (P8 @ XBT8^T)/l * contrib + xb16*(1-contrib).
// 1-D grid 512, XCD-swizzled: each XCD owns 2 n-tiles -> its XBT slice
// (1 MB) is L2-resident. Epilogue repacks via LDS for b128 stores.
__global__ __launch_bounds__(256) void gemm_recon_kernel(
    const unsigned char* __restrict__ P8, const unsigned char* __restrict__ XBT8,
    const bf16* __restrict__ XB16, const float* __restrict__ lrow,
    const float* __restrict__ contrib, bf16* __restrict__ R) {
  __shared__ unsigned char smem[65536];
  unsigned char* As0 = smem;
  unsigned char* Bs0 = smem + 16384;
  unsigned char* As1 = smem + 32768;
  unsigned char* Bs1 = smem + 49152;

  // XCD swizzle: id%8 = XCD (round-robin dispatch); give each XCD n-tiles
  // {xcd*2, xcd*2+1} so its XBT working set is 1 MB (fits 4 MB XCD L2).
  const int id = blockIdx.x;
  const int xcd = id & 7;
  const int s = id >> 3;
  const int bx = xcd * 2 + (s & 1);
  const int by = s >> 1;
  const int m0 = by * 128, n0 = bx * 128;

  floatx4 acc[4][4];
#pragma unroll
  for (int i = 0; i < 4; ++i)
#pragma unroll
    for (int j = 0; j < 4; ++j) acc[i][j] = 0.0f;

  gemm_core8(P8, XBT8, NB, m0, n0, As0, Bs0, As1, Bs1, acc);

  const int t = threadIdx.x, w = t >> 6, lane = t & 63;
  const int wm = w >> 1, wn = w & 1, lm = lane & 15, quad = lane >> 4;

  __syncthreads();  // waves done reading K-loop buffers; reuse smem
  bf16* osm = (bf16*)smem;
#pragma unroll
  for (int mi = 0; mi < 4; ++mi) {
#pragma unroll
    for (int r = 0; r < 4; ++r) {
      const int lrow_i = wm * 64 + mi * 16 + quad * 4 + r;
      const int grow = m0 + lrow_i;
      const float inv = 1.0f / lrow[grow];
      const float ci = contrib[grow];
#pragma unroll
      for (int ni = 0; ni < 4; ++ni) {
        const int lcol = wn * 64 + ni * 16 + lm;
        const float rec = acc[mi][ni][r] * inv;
        const float xv = (float)XB16[(size_t)grow * ND + n0 + lcol];
        osm[lrow_i * OS + lcol] = (bf16)(rec * ci + xv * (1.0f - ci));
      }
    }
  }
  __syncthreads();
#pragma unroll
  for (int it = 0; it < 8; ++it) {
    const int row = it * 16 + (t >> 4), ch = t & 15;
    int4 v = *(const int4*)(osm + row * OS + ch * 8);
    *(int4*)(R + (size_t)(m0 + row) * ND + n0 + ch * 8) = v;
  }
}

// Mix: x_mix = a*R[i] + (1-a)*R[beta[i]] (R in bf16). y_mix done in prep.
__global__ __launch_bounds__(256) void mix_kernel(
    const bf16* __restrict__ R, const float* __restrict__ alpha,
    const int* __restrict__ beta_idx, float* __restrict__ out) {
  const int i = blockIdx.x, t = threadIdx.x;
  const float a = alpha[i];
  const int bi = beta_idx[i];
  const bf16x8* Ri = (const bf16x8*)(R + (size_t)i * ND);
  const bf16x8* Rb = (const bf16x8*)(R + (size_t)bi * ND);
  const float b = 1.0f - a;
  bf16x8 r = Ri[t], g = Rb[t];
  float4 o0, o1;
  o0.x = a * (float)r[0] + b * (float)g[0];
  o0.y = a * (float)r[1] + b * (float)g[1];
  o0.z = a * (float)r[2] + b * (float)g[2];
  o0.w = a * (float)r[3] + b * (float)g[3];
  o1.x = a * (float)r[4] + b * (float)g[4];
  o1.y = a * (float)r[5] + b * (float)g[5];
  o1.z = a * (float)r[6] + b * (float)g[6];
  o1.w = a * (float)r[7] + b * (float)g[7];
  float4* o = (float4*)(out + (size_t)i * ND + t * 8);
  o[0] = o0;
  o[1] = o1;
}

// ------------------------------------------------------------------ launch --
extern "C" void kernel_launch(void* const* d_in, const int* in_sizes, int n_in,
                              void* d_out, int out_size, void* d_ws,
                              size_t ws_size, hipStream_t stream) {
  const float* x = (const float*)d_in[0];
  const int* y = (const int*)d_in[1];
  const float* alpha = (const float*)d_in[2];
  const int* beta = (const int*)d_in[3];
  const float* c = (const float*)d_in[4];
  const int* fs = (const int*)d_in[5];
  float* out = (float*)d_out;
  char* ws = (char*)d_ws;

  // workspace layout (bytes)
  unsigned char* XN8  = (unsigned char*)(ws + 0);         // 4096*2048 = 8 MiB
  unsigned char* XBT8 = (unsigned char*)(ws + 8388608);   // 2048*4096 = 8 MiB
  unsigned char* P8   = (unsigned char*)(ws + 16777216);  // 4096*4096 = 16 MiB
  bf16* R    = (bf16*)(ws + 33554432);                    // 4096*2048*2 = 16 MiB
  bf16* XB16 = (bf16*)(ws + 50331648);                    // 4096*2048*2 = 16 MiB
  float* LR = (float*)(ws + 67108864);                    // 4096*4
  float* CT = (float*)(ws + 67108864 + 16384);            // 4096*4
  int* MC   = (int*)(ws + 67108864 + 32768);              // 4096*4

  prep_kernel<<<NB + 2048 + 1024, 256, 0, stream>>>(x, y, alpha, beta, c, fs,
                                                    XN8, XBT8, XB16, LR, CT,
                                                    MC, out);
  gemm_sim_kernel<<<528, 256, 0, stream>>>(XN8, P8, LR, MC);
  gemm_recon_kernel<<<512, 256, 0, stream>>>(P8, XBT8, XB16, LR, CT, R);
  mix_kernel<<<NB, 256, 0, stream>>>(R, alpha, beta, out);
}